// Round 6
// baseline (241.703 us; speedup 1.0000x reference)
//
#include <hip/hip_runtime.h>
#include <cstdint>
#include <math.h>

// GeometricAttention: B=4,H=8,N=2048, D = 8*16 (mv, IPF signs on q) + 16 (s) = 144
// R9: counted-vmcnt double buffering (T3/T4). __syncthreads (which drains vmcnt(0)
// and re-locksteps the waves every iter -> sum-of-pipes ~105us across R4/R5/R7) is
// replaced by raw s_barrier + s_waitcnt vmcnt(N): each wave issues a FIXED number of
// global_load_lds per stage (waves 0-5: 5, waves 6-7: 6), so vmcnt(cnt) == "previous
// stage complete, newest still in flight". No vmcnt(0) in the main loop.
// K+V in one unified buffer (K@0, V@19456B, pad to 43008B) x2 = 86KB LDS.
// Body = R5's straight qk/sm/pv (R8's role skew regressed); R8's split packs kept.

#define BH    32
#define N_    2048
#define DMV   128
#define DS    16
#define D_    144
#define BM    256          // Q rows per block (8 waves x 32 rows)
#define BN    64           // KV rows per iteration
#define NKIT  (N_ / BN)    // 32
#define KSTR  152          // packed K row stride (bf16): 144 data + 8 pad
#define VSTR  72           // packed V^T row stride (bf16): 64 data + 8 pad
#define KP_BYTES ((size_t)BH * N_ * KSTR * 2)   // 19,922,944
#define QSCALE 0.12022458674074693f  // (1/12) * log2(e)
#define TSTR  156          // V-pack LDS transpose stride
// unified staging buffer: chunks of 16B. K: [0,1216), V(160 rows incl pad): [1216,2656),
// tail pad: [2656,2688). 2688*16 = 43008 B per buffer.
#define CK    1216
#define CV    2656
#define CTOT  2688
#define BUFE  (CTOT * 8)   // bf16 elems per buffer = 21504
#define VOFF  (CK * 8)     // V base elem offset = 9728

typedef __bf16 bf16_8 __attribute__((ext_vector_type(8)));
typedef __bf16 bf16_4 __attribute__((ext_vector_type(4)));
typedef __bf16 bf16_2 __attribute__((ext_vector_type(2)));
typedef float  f32x4  __attribute__((ext_vector_type(4)));
typedef float  f32x16 __attribute__((ext_vector_type(16)));

#define GLOAD_LDS16(g, l)                                                     \
  __builtin_amdgcn_global_load_lds(                                           \
      (const __attribute__((address_space(1))) void*)(g),                     \
      (__attribute__((address_space(3))) void*)(l), 16, 0, 0)

__device__ __forceinline__ f32x16 mfma32(bf16_8 a, bf16_8 b, f32x16 c) {
  return __builtin_amdgcn_mfma_f32_32x32x16_bf16(a, b, c, 0, 0, 0);
}

__device__ __forceinline__ bf16_4 cvt4(f32x4 x) {
  bf16_4 w; w[0]=(__bf16)x[0]; w[1]=(__bf16)x[1]; w[2]=(__bf16)x[2]; w[3]=(__bf16)x[3];
  return w;
}

// ---------------- pre-pass 1: K -> bf16 packed [bh*n][152] --------------------------
__global__ __launch_bounds__(256)
void pack_k(const float* __restrict__ kmv, const float* __restrict__ ks_,
            __bf16* __restrict__ kp) {
  const unsigned g = blockIdx.x * 256u + threadIdx.x;   // < 65536*19
  const unsigned row = g / 19u, seg = g - row * 19u;
  bf16_8 o;
  if (seg < 16) {
    const f32x4* p = (const f32x4*)(kmv + (size_t)row * DMV + seg * 8);
    f32x4 a = p[0], bb = p[1];
#pragma unroll
    for (int j = 0; j < 8; ++j) o[j] = (__bf16)((j < 4) ? a[j] : bb[j - 4]);
  } else if (seg < 18) {
    const f32x4* p = (const f32x4*)(ks_ + (size_t)row * DS + (seg - 16) * 8);
    f32x4 a = p[0], bb = p[1];
#pragma unroll
    for (int j = 0; j < 8; ++j) o[j] = (__bf16)((j < 4) ? a[j] : bb[j - 4]);
  } else {
#pragma unroll
    for (int j = 0; j < 8; ++j) o[j] = (__bf16)0.0f;
  }
  *(bf16_8*)(kp + (size_t)row * KSTR + seg * 8) = o;
}

// ---------------- pre-pass 2: V^T -> bf16 tile-blocked [bh*32 tiles][144][72] -------
__global__ __launch_bounds__(256)
void pack_vt(const float* __restrict__ vmv, const float* __restrict__ vs,
             __bf16* __restrict__ vt) {
  __shared__ __align__(16) __bf16 sT[64 * TSTR];
  const int tile = blockIdx.x;            // bh*32 + nb
  const int t = threadIdx.x;
  const int n = t >> 2, c = t & 3;
  const float* mv = vmv + (size_t)(tile * 64 + n) * DMV;
  const float* sv = vs  + (size_t)(tile * 64 + n) * DS;
  __bf16* row = &sT[n * TSTR];
  if (c < 3) {
#pragma unroll
    for (int i = 0; i < 9; ++i)
      *(bf16_4*)&row[c * 36 + 4 * i] = cvt4(*(const f32x4*)(mv + c * 36 + 4 * i));
  } else {
#pragma unroll
    for (int i = 0; i < 5; ++i)
      *(bf16_4*)&row[108 + 4 * i] = cvt4(*(const f32x4*)(mv + 108 + 4 * i));
#pragma unroll
    for (int i = 0; i < 4; ++i)
      *(bf16_4*)&row[128 + 4 * i] = cvt4(*(const f32x4*)(sv + 4 * i));
  }
  __syncthreads();
  __bf16* vtt = vt + (size_t)tile * (D_ * VSTR);
#pragma unroll
  for (int k = 0; k < 18; ++k) {
    int idx = t + 256 * k;                // 4608 = 144 d x 32 j-pairs
    int d = idx >> 5, j = idx & 31;
    bf16_2 p; p[0] = sT[(2 * j) * TSTR + d]; p[1] = sT[(2 * j + 1) * TSTR + d];
    *(bf16_2*)&vtt[d * VSTR + 2 * j] = p; // 128B contiguous per 32 lanes
  }
}

// ---------------- Q fragment load: IPF sign + scale, fp32 -> bf16 (k0 multiple of 8) --
__device__ __forceinline__ bf16_8 load_q_frag(const float* qmv_row, const float* qs_row, int k0) {
  bf16_8 f;
  if (k0 < DMV) {
    const f32x4* p = (const f32x4*)(qmv_row + k0);
    f32x4 a = p[0], b = p[1];
    // IPF = [1,1,-1,-1,-1,-1,-1,-1, 1,1,1,1,1,1,-1,-1]; k0&8 selects which half.
    int hi8 = k0 & 8;
#pragma unroll
    for (int j = 0; j < 8; ++j) {
      float v = (j < 4) ? a[j] : b[j - 4];
      bool pos = hi8 ? (j < 6) : (j < 2);
      f[j] = (__bf16)(v * (pos ? QSCALE : -QSCALE));
    }
  } else {
    const f32x4* p = (const f32x4*)(qs_row + (k0 - DMV));
    f32x4 a = p[0], b = p[1];
#pragma unroll
    for (int j = 0; j < 8; ++j) {
      float v = (j < 4) ? a[j] : b[j - 4];
      f[j] = (__bf16)(v * QSCALE);
    }
  }
  return f;
}

// ---------------- main flash kernel (512 threads, 8 waves x 32 Q-rows) ---------------
__global__ __launch_bounds__(512, 2)
void geo_attn_kernel(const float* __restrict__ q_mv, const float* __restrict__ q_s,
                     const __bf16* __restrict__ kp, const __bf16* __restrict__ vt,
                     float* __restrict__ out)
{
  __shared__ __align__(16) __bf16 sbuf[2][BUFE];   // 2 x 43008 B = 86016 B

  const int tid  = threadIdx.x;
  const int lane = tid & 63;
  const int w    = tid >> 6;
  const int c32  = lane & 31;
  const int hi   = lane >> 5;
  // XCD-chunked swizzle: all 8 q-blocks of a bh on one XCD (xcd = flat % 8)
  const int flat = blockIdx.x;           // 0..255
  const int xcd  = flat & 7;
  const int jj   = flat >> 3;            // 0..31
  const int bh   = xcd * 4 + (jj & 3);
  const int qb   = jj >> 2;              // 0..7
  const int qbase = qb * BM;
  const size_t bh_n = (size_t)bh * N_;

  // ---- Q fragments in registers: B-operand layout, col m = c32, k = ks*16 + hi*8 + j
  bf16_8 qf[9];
  {
    const int mrow = qbase + w * 32 + c32;
    const float* qmv_row = q_mv + (bh_n + mrow) * DMV;
    const float* qs_row  = q_s  + (bh_n + mrow) * DS;
#pragma unroll
    for (int ks = 0; ks < 9; ++ks)
      qf[ks] = load_q_frag(qmv_row, qs_row, ks * 16 + hi * 8);
  }

  f32x16 of[5];
#pragma unroll
  for (int dt = 0; dt < 5; ++dt)
#pragma unroll
    for (int r = 0; r < 16; ++r) of[dt][r] = 0.0f;
  float m_i = -INFINITY, l_i = 0.0f;    // per Q-row stat, row m = c32 (both hi copies)

  const __bf16* kbase = kp + bh_n * KSTR;
  const __bf16* vbase = vt + (size_t)bh * NKIT * (D_ * VSTR);

  // ---- staging: FIXED per-wave DMA instruction count (waves 0-5: 5, waves 6-7: 6).
  // chunk c -> lds sbuf[bu] + c*16B; src: K chunk, V chunk (wrapped), or recycled pad.
  auto stage = [&](int it, int bu) {
    const __bf16* kt  = kbase + (size_t)(it * BN) * KSTR;
    const __bf16* vtt = vbase + (size_t)it * (D_ * VSTR);
    if (w < 6) {
#pragma unroll
      for (int s = 0; s < 5; ++s) {
        int c = w * 320 + s * 64 + lane;
        const __bf16* src;
        if (c < CK) src = kt + c * 8;
        else { int vc = c - CK; if (vc >= 1296) vc -= 1296; src = vtt + vc * 8; }
        GLOAD_LDS16(src, &sbuf[bu][c * 8]);
      }
    } else {
#pragma unroll
      for (int s = 0; s < 6; ++s) {
        int c = 1920 + (w - 6) * 384 + s * 64 + lane;
        const __bf16* src;
        if (c < CK) src = kt + c * 8;
        else { int vc = c - CK; if (vc >= 1296) vc -= 1296; src = vtt + vc * 8; }
        GLOAD_LDS16(src, &sbuf[bu][c * 8]);
      }
    }
  };
  auto wait_prev_stage = [&]() {   // newest stage's loads (5 or 6) may stay in flight
    if (w < 6) asm volatile("s_waitcnt vmcnt(5)" ::: "memory");
    else       asm volatile("s_waitcnt vmcnt(6)" ::: "memory");
  };

  // QK(t): S^T rows n = nt*32 + (r&3)+8*(r>>2)+4*hi, cols m = c32
  f32x16 sf[2];
  auto qk = [&](int bu) {
    const __bf16* sKt = &sbuf[bu][0];
#pragma unroll
    for (int nt = 0; nt < 2; ++nt)
#pragma unroll
      for (int r = 0; r < 16; ++r) sf[nt][r] = 0.0f;
    __builtin_amdgcn_s_setprio(1);
#pragma unroll
    for (int ks = 0; ks < 9; ++ks) {
      bf16_8 kb0 = *(const bf16_8*)&sKt[(c32)      * KSTR + ks * 16 + hi * 8];
      bf16_8 kb1 = *(const bf16_8*)&sKt[(32 + c32) * KSTR + ks * 16 + hi * 8];
      sf[0] = mfma32(kb0, qf[ks], sf[0]);
      sf[1] = mfma32(kb1, qf[ks], sf[1]);
    }
    __builtin_amdgcn_s_setprio(0);
  };

  // softmax on sf: depth-5 trees, deferred rescale (T13, THR=8)
  auto sm = [&]() {
    float al = 1.0f, m_use;
    float a[8];
#pragma unroll
    for (int r = 0; r < 8; ++r)
      a[r] = fmaxf(fmaxf(sf[0][r], sf[0][r + 8]), fmaxf(sf[1][r], sf[1][r + 8]));
    float mx = fmaxf(fmaxf(fmaxf(a[0], a[1]), fmaxf(a[2], a[3])),
                     fmaxf(fmaxf(a[4], a[5]), fmaxf(a[6], a[7])));
    mx = fmaxf(mx, __shfl_xor(mx, 32));

    if (__all(mx <= m_i + 8.0f)) {
      m_use = m_i;
    } else {
      float mnew = fmaxf(m_i, mx);
      al = __builtin_amdgcn_exp2f(m_i - mnew);
      m_i = mnew; m_use = mnew;
#pragma unroll
      for (int r = 0; r < 16; ++r) {
        float aa = __shfl(al, (r & 3) + 8 * (r >> 2) + 4 * hi);
#pragma unroll
        for (int dt = 0; dt < 5; ++dt) of[dt][r] *= aa;
      }
    }
#pragma unroll
    for (int nt = 0; nt < 2; ++nt)
#pragma unroll
      for (int r = 0; r < 16; ++r)
        sf[nt][r] = __builtin_amdgcn_exp2f(sf[nt][r] - m_use);
    float s8[8];
#pragma unroll
    for (int r = 0; r < 8; ++r)
      s8[r] = (sf[0][r] + sf[0][r + 8]) + (sf[1][r] + sf[1][r + 8]);
    float rs = ((s8[0] + s8[1]) + (s8[2] + s8[3])) + ((s8[4] + s8[5]) + (s8[6] + s8[7]));
    rs += __shfl_xor(rs, 32);
    l_i = l_i * al + rs;
  };

  // PV: P in-register (cvt_pk + permlane32_swap), V from sbuf[bu]+VOFF
  auto pv = [&](int bu) {
    const __bf16* sV = &sbuf[bu][VOFF];
#pragma unroll
    for (int ks = 0; ks < 4; ++ks) {
      const int nt = ks >> 1;
      const int Ra = 8 * (ks & 1);
      unsigned x0, x1, y0, y1;
      asm("v_cvt_pk_bf16_f32 %0, %1, %2" : "=v"(x0) : "v"(sf[nt][Ra + 0]), "v"(sf[nt][Ra + 1]));
      asm("v_cvt_pk_bf16_f32 %0, %1, %2" : "=v"(x1) : "v"(sf[nt][Ra + 2]), "v"(sf[nt][Ra + 3]));
      asm("v_cvt_pk_bf16_f32 %0, %1, %2" : "=v"(y0) : "v"(sf[nt][Ra + 4]), "v"(sf[nt][Ra + 5]));
      asm("v_cvt_pk_bf16_f32 %0, %1, %2" : "=v"(y1) : "v"(sf[nt][Ra + 6]), "v"(sf[nt][Ra + 7]));
      auto s0 = __builtin_amdgcn_permlane32_swap(x0, y0, false, false);
      auto s1 = __builtin_amdgcn_permlane32_swap(x1, y1, false, false);
      union { unsigned u[4]; bf16_8 v; } pu;
      pu.u[0] = s0[0]; pu.u[1] = s1[0]; pu.u[2] = s0[1]; pu.u[3] = s1[1];
      __builtin_amdgcn_s_setprio(1);
#pragma unroll
      for (int dt = 0; dt < 5; ++dt) {
        bf16_8 vb = *(const bf16_8*)&sV[(dt * 32 + c32) * VSTR + ks * 16 + hi * 8];
        of[dt] = mfma32(pu.v, vb, of[dt]);
      }
      __builtin_amdgcn_s_setprio(0);
    }
  };

  // ---- prologue: stage 0 and 1; wait for 0 only (1 stays in flight) ----
  stage(0, 0);
  stage(1, 1);
  wait_prev_stage();
  __builtin_amdgcn_s_barrier();

  for (int t = 0; t < NKIT; ++t) {
    const int cur = t & 1;
    qk(cur); sm(); pv(cur);

    // all waves done reading buf[cur]; then refill it with tile t+2
    asm volatile("s_waitcnt lgkmcnt(0)" ::: "memory");
    __builtin_amdgcn_s_barrier();
    if (t + 2 < NKIT) {
      stage(t + 2, cur);
      wait_prev_stage();                 // stage(t+1) done, stage(t+2) in flight
    } else {
      asm volatile("s_waitcnt vmcnt(0)" ::: "memory");   // last 2 iters only
    }
    __builtin_amdgcn_s_barrier();        // tile t+1 resident for everyone
  }

  // ======== epilogue: O /= l (redistributed to O-rows), write fp32 ========
  float* out_mv = out;
  float* out_s  = out + (size_t)BH * N_ * DMV;
#pragma unroll
  for (int r = 0; r < 16; ++r) {
    const int ml  = (r & 3) + 8 * (r >> 2) + 4 * hi;
    const float linv = __builtin_amdgcn_rcpf(__shfl(l_i, ml));
    const int row = qbase + w * 32 + ml;
#pragma unroll
    for (int dt = 0; dt < 4; ++dt)
      out_mv[(bh_n + row) * DMV + dt * 32 + c32] = of[dt][r] * linv;
    if (c32 < DS)
      out_s[(bh_n + row) * DS + c32] = of[4][r] * linv;
  }
}

extern "C" void kernel_launch(void* const* d_in, const int* in_sizes, int n_in,
                              void* d_out, int out_size, void* d_ws, size_t ws_size,
                              hipStream_t stream) {
  (void)in_sizes; (void)n_in; (void)out_size; (void)ws_size;
  const float* q_mv = (const float*)d_in[0];
  const float* k_mv = (const float*)d_in[1];
  const float* v_mv = (const float*)d_in[2];
  const float* q_s  = (const float*)d_in[3];
  const float* k_s  = (const float*)d_in[4];
  const float* v_s  = (const float*)d_in[5];
  float* out = (float*)d_out;

  __bf16* kp = (__bf16*)d_ws;                              // 19,922,944 B
  __bf16* vt = (__bf16*)((char*)d_ws + KP_BYTES);          // 21,233,664 B

  pack_k<<<(BH * N_ * 19) / 256, 256, 0, stream>>>(k_mv, k_s, kp);
  pack_vt<<<BH * NKIT, 256, 0, stream>>>(v_mv, v_s, vt);

  geo_attn_kernel<<<dim3(256), 512, 0, stream>>>(q_mv, q_s, kp, vt, out);
}